// Round 18
// baseline (478.684 us; speedup 1.0000x reference)
//
#include <hip/hip_runtime.h>
#include <hip/hip_bf16.h>
#include <cfloat>

#define CH   1024
#define HW   4096
#define NSVD 500
#define TFR  3
#define SREF 2

typedef __attribute__((ext_vector_type(4))) float f32x4;
typedef __attribute__((ext_vector_type(2))) unsigned int u32x2;
typedef __attribute__((ext_vector_type(4))) unsigned int u32x4;
typedef __attribute__((ext_vector_type(8))) short short8;

// ---------------------------------------------------------------------------
// Split-bf16 planes in BLOCKED layout: plane[cb][kgrp][cl][kp4] u32.
// fh/fl frames 0,1 = packed fn_refs; frame 2 = packed RAW Xd (written by
// gemm3r). Packed fn_tgt lives in SEPARATE Tgt planes (d_out scratch) so
// gemm3r never reads and writes the same buffer (R17 race fixed).
// invxd applied as COLUMN scale in simg epilogue / votes_k (argmax-safe).
// 3-PASS numerics (hh + h*lo(B) + lo(A)*h), proven vote-safe. DETERMINISTIC.
// ws (float units): fh 0 / fl 6,291,456 / invc 12,595,200 (3*HW) /
//   protos 12,607,552 / proto 12,611,648 / am 12,612,672 (2*HW u64) /
//   part 12,629,056 (8*2048) / counts 12,645,440 / sfpart 12,645,504 (4*HW)
//   -> end 12,661,888 (proven envelope)
// d_out scratch (all dead before simg writes sim): Ach 0, Acl 786,432,
//   bt 1,572,864, TgtH 5,767,168, TgtL 7,864,320, pbuf 9,961,472 (24*HW)
// ---------------------------------------------------------------------------

__device__ inline unsigned bfr(float x) {        // fp32 -> bf16 bits, RNE
  unsigned u = __float_as_uint(x);
  return (u + 0x7fffu + ((u >> 16) & 1u)) >> 16;
}
__device__ inline float lores(float x, unsigned h) {
  return x - __uint_as_float(h << 16);
}
__device__ inline float vlo(unsigned ph, unsigned pl) {
  return __uint_as_float(ph << 16) + __uint_as_float(pl << 16);
}
__device__ inline float vhi(unsigned ph, unsigned pl) {
  return __uint_as_float(ph & 0xFFFF0000u) + __uint_as_float(pl & 0xFFFF0000u);
}

// Fused column-l2norm + scale + split-bf16 blocked pack.
// Writes frame (fbase + blockIdx.x>>6) of the given plane pair.
__global__ __launch_bounds__(256) void normpack_k(const float* __restrict__ src,
                                                  unsigned* __restrict__ Gh,
                                                  unsigned* __restrict__ Gl,
                                                  int fbase) {
  int t = blockIdx.x >> 6;
  int n0 = (blockIdx.x & 63) * 64;
  int tid = threadIdx.x, nl = tid & 63, r = tid >> 6;
  const float* base = src + (size_t)t * CH * HW + n0 + nl;
  float s = 0.f;
  for (int c = r; c < CH; c += 4) {
    float v = base[(size_t)c * HW];
    s += v * v;
  }
  __shared__ float red[256];
  __shared__ float inv[64];
  red[tid] = s;
  __syncthreads();
  if (r == 0)
    inv[nl] = 1.0f / fmaxf(sqrtf(red[nl] + red[nl + 64] + red[nl + 128] + red[nl + 192]), 1e-12f);
  __syncthreads();

  int cg = (tid & 15) * 4;
  int n4 = n0 + cg;
  float4 w4;
  w4.x = inv[cg]; w4.y = inv[cg + 1]; w4.z = inv[cg + 2]; w4.w = inv[cg + 3];
  int gt = fbase + t;
  for (int kg = tid >> 4; kg < 128; kg += 16) {
    const float* s0 = src + ((size_t)t * CH + kg * 8) * HW + n4;
    unsigned oh[4][4], ol[4][4];
#pragma unroll
    for (int j = 0; j < 4; j++) {
      float4 va = *reinterpret_cast<const float4*>(s0 + (size_t)(2 * j) * HW);
      float4 vb = *reinterpret_cast<const float4*>(s0 + (size_t)(2 * j + 1) * HW);
      float a[4] = {va.x * w4.x, va.y * w4.y, va.z * w4.z, va.w * w4.w};
      float b[4] = {vb.x * w4.x, vb.y * w4.y, vb.z * w4.z, vb.w * w4.w};
#pragma unroll
      for (int cc = 0; cc < 4; cc++) {
        unsigned ha = bfr(a[cc]), hb = bfr(b[cc]);
        oh[cc][j] = ha | (hb << 16);
        ol[cc][j] = bfr(lores(a[cc], ha)) | (bfr(lores(b[cc], hb)) << 16);
      }
    }
    size_t vib = (((size_t)gt * 16 + (n4 >> 8)) * 128 + kg) * 256 + (n4 & 255);
#pragma unroll
    for (int cc = 0; cc < 4; cc++) {
      *reinterpret_cast<u32x4*>(Gh + (vib + cc) * 4) = *reinterpret_cast<u32x4*>(oh[cc]);
      *reinterpret_cast<u32x4*>(Gl + (vib + cc) * 4) = *reinterpret_cast<u32x4*>(ol[cc]);
    }
  }
}

// bt[k][c] = (k<500) ? basis[c][k] : 0   (LDS tile transpose)
__global__ __launch_bounds__(256) void bt_k(const float* __restrict__ bas,
                                            float* __restrict__ bt) {
  int c0 = blockIdx.x * 64;
  __shared__ float tile[64][129];
  int tid = threadIdx.x;
  for (int kc = 0; kc < 512; kc += 128) {
    for (int cr = tid >> 7; cr < 64; cr += 2) {
      int k = kc + (tid & 127);
      tile[cr][tid & 127] = (k < NSVD) ? bas[(size_t)(c0 + cr) * NSVD + k] : 0.f;
    }
    __syncthreads();
    for (int kr = tid >> 6; kr < 128; kr += 4)
      bt[(size_t)(kc + kr) * 1024 + c0 + (tid & 63)] = tile[tid & 63][kr];
    __syncthreads();
  }
}

// Acomb cols 0..1023: P = I - basis@basis^T, blocked write (coalesced bt reads)
__global__ __launch_bounds__(256) void proj_pack_k(const float* __restrict__ bt,
                                                   unsigned* __restrict__ Ah,
                                                   unsigned* __restrict__ Al) {
  int m0 = blockIdx.x * 64, n0 = blockIdx.y * 64;
  int tid = threadIdx.x;
  int tx = tid & 15, ty = tid >> 4;
  int lm = tid & 63, lk = tid >> 6;
  __shared__ float As[16][64];
  __shared__ float Bs[16][64];
  float acc[4][4] = {};
  for (int k0 = 0; k0 < 512; k0 += 16) {
#pragma unroll
    for (int i = 0; i < 4; i++) {
      int k = k0 + lk * 4 + i;
      As[lk * 4 + i][lm] = bt[(size_t)k * 1024 + m0 + lm];
      Bs[lk * 4 + i][lm] = bt[(size_t)k * 1024 + n0 + lm];
    }
    __syncthreads();
#pragma unroll
    for (int kk = 0; kk < 16; kk++) {
      float a[4], b[4];
#pragma unroll
      for (int i = 0; i < 4; i++) a[i] = As[kk][ty * 4 + i];
#pragma unroll
      for (int j = 0; j < 4; j++) b[j] = Bs[kk][tx * 4 + j];
#pragma unroll
      for (int i = 0; i < 4; i++)
#pragma unroll
        for (int j = 0; j < 4; j++) acc[i][j] += a[i] * b[j];
    }
    __syncthreads();
  }
#pragma unroll
  for (int jp = 0; jp < 2; jp++) {
    int r = n0 / 2 + tx * 2 + jp;
#pragma unroll
    for (int i = 0; i < 4; i++) {
      int c = m0 + ty * 4 + i;
      float va = ((c == 2 * r) ? 1.0f : 0.0f) - acc[i][2 * jp];
      float vb = ((c == 2 * r + 1) ? 1.0f : 0.0f) - acc[i][2 * jp + 1];
      unsigned ha = bfr(va), hb = bfr(vb);
      size_t vi = ((size_t)((c >> 8) * 128 + (r >> 2)) * 256 + (c & 255)) * 4 + (r & 3);
      Ah[vi] = ha | (hb << 16);
      Al[vi] = bfr(lores(va, ha)) | (bfr(lores(vb, hb)) << 16);
    }
  }
}

// Acomb cols 1024..1535: basis zero-padded to 512 svd rows
__global__ __launch_bounds__(256) void pack_basis_k(const float* __restrict__ bas,
                                                    unsigned* __restrict__ Ah,
                                                    unsigned* __restrict__ Al) {
  int r = blockIdx.x;
  for (int m = threadIdx.x; m < 512; m += 256) {
    float b0 = (m < NSVD) ? bas[(size_t)(2 * r) * NSVD + m] : 0.f;
    float b1 = (m < NSVD) ? bas[(size_t)(2 * r + 1) * NSVD + m] : 0.f;
    unsigned h0 = bfr(b0), h1 = bfr(b1);
    int c = 1024 + m;
    size_t vi = ((size_t)((c >> 8) * 128 + (r >> 2)) * 256 + (c & 255)) * 4 + (r & 3);
    Ah[vi] = h0 | (h1 << 16);
    Al[vi] = bfr(lores(b0, h0)) | (bfr(lores(b1, h1)) << 16);
  }
}

// invc from pbuf partials (fixed-order sums -> deterministic).
__global__ __launch_bounds__(256) void inv2_k(const float* __restrict__ pbuf,
                                              float* __restrict__ invc) {
  int i = blockIdx.x * 256 + threadIdx.x;
  int s = i >> 12, n = i & 4095;
  float s2 = 0.f;
  if (s < 2) {
#pragma unroll
    for (int j = 0; j < 4; j++) s2 += pbuf[(size_t)(s * 8 + j) * HW + n];
    s2 = sqrtf(fmaxf(1.0f - s2, 0.0f));
  } else {
#pragma unroll
    for (int j = 16; j < 24; j++) s2 += pbuf[(size_t)j * HW + n];
    s2 = sqrtf(s2);
  }
  invc[i] = 1.0f / fmaxf(s2, 1e-12f);
}

// protos[s*CH+c] = sum_n mask*fn*invc; block = (s, kgrp); kg==0 also counts
__global__ __launch_bounds__(256) void proto_k(const unsigned* __restrict__ Gh,
                                               const unsigned* __restrict__ Gl,
                                               const int* __restrict__ mask,
                                               const float* __restrict__ invc,
                                               float* __restrict__ protos,
                                               float* __restrict__ counts) {
  int s = blockIdx.x >> 7, kg = blockIdx.x & 127;
  int tid = threadIdx.x;
  const u32x4* Hv = (const u32x4*)Gh + (size_t)s * 524288;
  const u32x4* Lv = (const u32x4*)Gl + (size_t)s * 524288;
  float a[8] = {};
  int cnt = 0;
  for (int n = tid; n < HW; n += 256) {
    if (mask[s * HW + n]) {
      cnt++;
      float w = invc[s * HW + n];
      size_t vi = ((size_t)(n >> 8) * 128 + kg) * 256 + (n & 255);
      u32x4 h = Hv[vi], l = Lv[vi];
#pragma unroll
      for (int j = 0; j < 4; j++) {
        a[2 * j] += vlo(h[j], l[j]) * w;
        a[2 * j + 1] += vhi(h[j], l[j]) * w;
      }
    }
  }
  __shared__ float red[256];
  for (int e = 0; e < 8; e++) {
    red[tid] = a[e];
    __syncthreads();
    for (int o = 128; o > 0; o >>= 1) {
      if (tid < o) red[tid] += red[tid + o];
      __syncthreads();
    }
    if (tid == 0) protos[s * CH + kg * 8 + e] = red[0];
    __syncthreads();
  }
  if (kg == 0) {
    red[tid] = (float)cnt;
    __syncthreads();
    for (int o = 128; o > 0; o >>= 1) {
      if (tid < o) red[tid] += red[tid + o];
      __syncthreads();
    }
    if (tid == 0) counts[s] = fmaxf(red[0], 1.0f);
  }
}

// part[kc][s*CH+c] = sum_{r in kc-chunk} P[c][k]*protos[s][k]; grid (8, 8)
__global__ __launch_bounds__(256) void protomv_k(const unsigned* __restrict__ Ah,
                                                 const unsigned* __restrict__ Al,
                                                 const float* __restrict__ protos,
                                                 float* __restrict__ part) {
  int s = blockIdx.x >> 2;
  int c = (blockIdx.x & 3) * 256 + threadIdx.x;
  int kc = blockIdx.y;
  __shared__ float w[128];
  if (threadIdx.x < 128) w[threadIdx.x] = protos[s * CH + kc * 128 + threadIdx.x];
  __syncthreads();
  float acc = 0.f;
  for (int rl = 0; rl < 64; rl++) {
    int r = kc * 64 + rl;
    size_t vi = ((size_t)((c >> 8) * 128 + (r >> 2)) * 256 + (c & 255)) * 4 + (r & 3);
    unsigned h = Ah[vi], l = Al[vi];
    acc += vlo(h, l) * w[2 * rl] + vhi(h, l) * w[2 * rl + 1];
  }
  part[kc * 2048 + s * CH + c] = acc;
}

// partial-sum reduce + mean + l2norm (1 block; counts precomputed)
__global__ __launch_bounds__(256) void protonorm_k(const float* __restrict__ part,
                                                   const float* __restrict__ counts,
                                                   float* __restrict__ proto) {
  int tid = threadIdx.x;
  __shared__ float sm[CH];
  __shared__ float red[256];
  float c0 = counts[0], c1 = counts[1];
  float ss = 0.f;
  for (int c = tid; c < CH; c += 256) {
    float p0 = 0.f, p1 = 0.f;
#pragma unroll
    for (int kc = 0; kc < 8; kc++) {
      p0 += part[kc * 2048 + c];
      p1 += part[kc * 2048 + CH + c];
    }
    float m = 0.5f * (p0 / c0 + p1 / c1);
    sm[c] = m;
    ss += m * m;
  }
  red[tid] = ss;
  __syncthreads();
  for (int o = 128; o > 0; o >>= 1) {
    if (tid < o) red[tid] += red[tid + o];
    __syncthreads();
  }
  __syncthreads();
  float inv = 1.0f / fmaxf(sqrtf(red[0]), 1e-12f);
  for (int c = tid; c < CH; c += 256) proto[c] = sm[c] * inv;
}

// sim_fwd partials on RAW Xd planes (frame 2): grid (64, 4)
__global__ __launch_bounds__(256) void simfwd_k(const unsigned* __restrict__ Gh,
                                                const unsigned* __restrict__ Gl,
                                                const float* __restrict__ proto,
                                                float* __restrict__ sfpart) {
  int q = blockIdx.y;
  __shared__ float p[256];
  __shared__ float red[256];
  int tid = threadIdx.x;
  p[tid] = proto[q * 256 + tid];
  __syncthreads();
  int nl = tid & 63, sub = tid >> 6;
  int n = blockIdx.x * 64 + nl;
  const u32x4* Hv = (const u32x4*)Gh + (size_t)2 * 524288;
  const u32x4* Lv = (const u32x4*)Gl + (size_t)2 * 524288;
  float acc = 0.f;
  for (int kg = q * 32 + sub * 8; kg < q * 32 + sub * 8 + 8; kg++) {
    size_t vi = ((size_t)(n >> 8) * 128 + kg) * 256 + (n & 255);
    u32x4 h = Hv[vi], l = Lv[vi];
    int pb = (kg - q * 32) * 8;
#pragma unroll
    for (int j = 0; j < 4; j++)
      acc += vlo(h[j], l[j]) * p[pb + 2 * j] + vhi(h[j], l[j]) * p[pb + 2 * j + 1];
  }
  red[tid] = acc;
  __syncthreads();
  if (sub == 0)
    sfpart[(size_t)q * HW + n] = red[nl] + red[nl + 64] + red[nl + 128] + red[nl + 192];
}

// ---------------------------------------------------------------------------
// Debias GEMM, LDS-FREE register pipeline: 128x256 tiles, 8 waves x 64x64.
// z<2 (refs): A = basis cols of Acomb, B = fn_refs (fh/fl frames 0,1).
// z==2 (Xd):  A = P cols of Acomb, B = fn_tgt from SEPARATE Tgt planes;
//   packs RAW Xd directly into fh/fl frame 2 (disjoint from all reads).
// s2 partials -> pbuf (plain stores). DETERMINISTIC.
// ---------------------------------------------------------------------------
#define G3_NT 32

__global__ __launch_bounds__(512, 2) void gemm3r_k(
    const unsigned* __restrict__ Ach, const unsigned* __restrict__ Acl,
    unsigned* __restrict__ fh, unsigned* __restrict__ fl,
    const unsigned* __restrict__ TgtH, const unsigned* __restrict__ TgtL,
    float* __restrict__ pbuf) {
  int orig = blockIdx.x;                       // 0..255
  int lin = (orig & 7) * 32 + (orig >> 3);     // XCD-contiguous, bijective
  int z, bx, by;
  if (lin < 128) { z = lin >> 6; bx = (lin >> 4) & 3; by = lin & 15; }
  else { int l2 = lin - 128; z = 2; bx = l2 >> 4; by = l2 & 15; }
  bool isXd = (z == 2);
  int acol0 = isXd ? bx * 128 : 1024 + bx * 128;
  int acb = acol0 >> 8, aco = acol0 & 255;

  const unsigned* Agh = Ach + (size_t)acb * 131072;
  const unsigned* Agl = Acl + (size_t)acb * 131072;
  const unsigned* Bgh = isXd ? TgtH + (size_t)by * 131072
                             : fh + (size_t)z * 2097152 + (size_t)by * 131072;
  const unsigned* Bgl = isXd ? TgtL + (size_t)by * 131072
                             : fl + (size_t)z * 2097152 + (size_t)by * 131072;

  int tid = threadIdx.x, ln = tid & 63, wv = tid >> 6;
  int wr = wv >> 2, wc = wv & 3;
  int fcol = ln & 15, l16 = ln >> 4;
  int aoff = l16 * 1024 + (aco + wr * 64 + fcol) * 4;   // + mf*64
  int boff = l16 * 1024 + (wc * 64 + fcol) * 4;         // + nf*64

  f32x4 acc[4][4] = {};
  u32x4 ahr[4], alr[4], bhr[4], blr[4];

#define MFMA16R(A, B)                                                         \
  _Pragma("unroll")                                                           \
  for (int mf = 0; mf < 4; mf++)                                              \
    _Pragma("unroll")                                                         \
    for (int nf = 0; nf < 4; nf++)                                            \
      acc[mf][nf] = __builtin_amdgcn_mfma_f32_16x16x32_bf16(                  \
          __builtin_bit_cast(short8, A[mf]), __builtin_bit_cast(short8, B[nf]), \
          acc[mf][nf], 0, 0, 0);

#pragma unroll
  for (int mf = 0; mf < 4; mf++)
    ahr[mf] = *reinterpret_cast<const u32x4*>(Agh + aoff + mf * 64);
#pragma unroll
  for (int nf = 0; nf < 4; nf++)
    blr[nf] = *reinterpret_cast<const u32x4*>(Bgl + boff + nf * 64);
#pragma unroll
  for (int nf = 0; nf < 4; nf++)
    bhr[nf] = *reinterpret_cast<const u32x4*>(Bgh + boff + nf * 64);
#pragma unroll
  for (int mf = 0; mf < 4; mf++)
    alr[mf] = *reinterpret_cast<const u32x4*>(Agl + aoff + mf * 64);

  for (int t = 0; t < G3_NT; ++t) {
    int nxt = (t + 1) * 4096;

    __builtin_amdgcn_s_setprio(1);
    MFMA16R(ahr, bhr)
    __builtin_amdgcn_s_setprio(0);
    __builtin_amdgcn_sched_barrier(0);

    __builtin_amdgcn_s_setprio(1);
    MFMA16R(ahr, blr)
    __builtin_amdgcn_s_setprio(0);
    __builtin_amdgcn_sched_barrier(0);
    if (t + 1 < G3_NT) {
#pragma unroll
      for (int mf = 0; mf < 4; mf++)
        ahr[mf] = *reinterpret_cast<const u32x4*>(Agh + nxt + aoff + mf * 64);
#pragma unroll
      for (int nf = 0; nf < 4; nf++)
        blr[nf] = *reinterpret_cast<const u32x4*>(Bgl + nxt + boff + nf * 64);
    }
    __builtin_amdgcn_sched_barrier(0);

    __builtin_amdgcn_s_setprio(1);
    MFMA16R(alr, bhr)
    __builtin_amdgcn_s_setprio(0);
    __builtin_amdgcn_sched_barrier(0);
    if (t + 1 < G3_NT) {
#pragma unroll
      for (int nf = 0; nf < 4; nf++)
        bhr[nf] = *reinterpret_cast<const u32x4*>(Bgh + nxt + boff + nf * 64);
#pragma unroll
      for (int mf = 0; mf < 4; mf++)
        alr[mf] = *reinterpret_cast<const u32x4*>(Agl + nxt + aoff + mf * 64);
    }
    __builtin_amdgcn_sched_barrier(0);
  }
#undef MFMA16R

  // epilogue: per-column s2; Xd blocks pack raw values into frame-2 planes
  int n0 = by * 256;
  unsigned* Gh2 = fh + (size_t)2 * 2097152;
  unsigned* Gl2 = fl + (size_t)2 * 2097152;
  float s2p[4] = {0.f, 0.f, 0.f, 0.f};
#pragma unroll
  for (int mf = 0; mf < 4; mf++) {
    int kpb = bx * 64 + wr * 32 + mf * 8 + l16 * 2;   // global kpair base (even)
#pragma unroll
    for (int nf = 0; nf < 4; nf++) {
      float v0 = acc[mf][nf][0], v1 = acc[mf][nf][1];
      float v2 = acc[mf][nf][2], v3 = acc[mf][nf][3];
      s2p[nf] += v0 * v0 + v1 * v1 + v2 * v2 + v3 * v3;
      if (isXd) {
        int n = n0 + wc * 64 + nf * 16 + fcol;
        unsigned h0 = bfr(v0), h1 = bfr(v1), h2 = bfr(v2), h3 = bfr(v3);
        u32x2 oh = {h0 | (h1 << 16), h2 | (h3 << 16)};
        u32x2 ol = {bfr(lores(v0, h0)) | (bfr(lores(v1, h1)) << 16),
                    bfr(lores(v2, h2)) | (bfr(lores(v3, h3)) << 16)};
        size_t vi = ((size_t)((n >> 8) * 128 + (kpb >> 2)) * 256 + (n & 255)) * 4 + (kpb & 3);
        *reinterpret_cast<u32x2*>(Gh2 + vi) = oh;
        *reinterpret_cast<u32x2*>(Gl2 + vi) = ol;
      }
    }
  }
#pragma unroll
  for (int nf = 0; nf < 4; nf++) {
    s2p[nf] += __shfl_xor(s2p[nf], 16, 64);
    s2p[nf] += __shfl_xor(s2p[nf], 32, 64);
  }
  __shared__ float sred[256];
  if (wr == 0 && l16 == 0) {
#pragma unroll
    for (int nf = 0; nf < 4; nf++) sred[wc * 64 + nf * 16 + fcol] = s2p[nf];
  }
  __syncthreads();
  if (wr == 1 && l16 == 0) {
    int slot = isXd ? 16 + bx : z * 8 + bx;
    float* dst = pbuf + (size_t)slot * HW + n0;
#pragma unroll
    for (int nf = 0; nf < 4; nf++) {
      int col = wc * 64 + nf * 16 + fcol;
      dst[col] = sred[col] + s2p[nf];
    }
  }
}

// ---------------------------------------------------------------------------
// sim GEMM (proven): 256x256 tile, 8 waves, 3-pass, LDS-FREE, 16x16x32 MFMA,
// in-place register rotation, row scale (invr) x column scale (invxd),
// fused atomic argmax.
// ---------------------------------------------------------------------------
#define SIMG_NT 32

__global__ __launch_bounds__(512, 2) void simg_k(
    const unsigned* __restrict__ Gh, const unsigned* __restrict__ Gl,
    const float* __restrict__ invc, float* __restrict__ simout,
    unsigned long long* __restrict__ amg) {
  int orig = (blockIdx.z * 16 + blockIdx.y) * 16 + blockIdx.x;
  int lin = (orig & 7) * 64 + (orig >> 3);         // XCD-contiguous, bijective
  int z = lin >> 8, bx = (lin >> 4) & 15, by = lin & 15;

  const unsigned* Agh = Gh + (size_t)z * 2097152 + (size_t)bx * 131072;
  const unsigned* Agl = Gl + (size_t)z * 2097152 + (size_t)bx * 131072;
  const unsigned* Bgh = Gh + (size_t)2 * 2097152 + (size_t)by * 131072;
  const unsigned* Bgl = Gl + (size_t)2 * 2097152 + (size_t)by * 131072;

  int tid = threadIdx.x, ln = tid & 63, wv = tid >> 6;
  int wr = wv >> 2, wc = wv & 3;
  int fcol = ln & 15, l16 = ln >> 4;
  int aoff = l16 * 1024 + (wr * 128 + fcol) * 4;   // + mf*64 (u32 units)
  int boff = l16 * 1024 + (wc * 64 + fcol) * 4;    // + nf*64

  f32x4 acc[8][4] = {};
  u32x4 ahr[8], alr[8], bhr[4], blr[4];

#define MFMA32(A, B)                                                          \
  _Pragma("unroll")                                                           \
  for (int mf = 0; mf < 8; mf++)                                              \
    _Pragma("unroll")                                                         \
    for (int nf = 0; nf < 4; nf++)                                            \
      acc[mf][nf] = __builtin_amdgcn_mfma_f32_16x16x32_bf16(                  \
          __builtin_bit_cast(short8, A[mf]), __builtin_bit_cast(short8, B[nf]), \
          acc[mf][nf], 0, 0, 0);

#pragma unroll
  for (int mf = 0; mf < 8; mf++)
    ahr[mf] = *reinterpret_cast<const u32x4*>(Agh + aoff + mf * 64);
#pragma unroll
  for (int nf = 0; nf < 4; nf++)
    blr[nf] = *reinterpret_cast<const u32x4*>(Bgl + boff + nf * 64);
#pragma unroll
  for (int nf = 0; nf < 4; nf++)
    bhr[nf] = *reinterpret_cast<const u32x4*>(Bgh + boff + nf * 64);
#pragma unroll
  for (int mf = 0; mf < 8; mf++)
    alr[mf] = *reinterpret_cast<const u32x4*>(Agl + aoff + mf * 64);

  for (int t = 0; t < SIMG_NT; ++t) {
    int nxt = (t + 1) * 4096;

    // P0: hi(A) x hi(B)
    __builtin_amdgcn_s_setprio(1);
    MFMA32(ahr, bhr)
    __builtin_amdgcn_s_setprio(0);
    __builtin_amdgcn_sched_barrier(0);

    // P1: hi(A) x lo(B)
    __builtin_amdgcn_s_setprio(1);
    MFMA32(ahr, blr)
    __builtin_amdgcn_s_setprio(0);
    __builtin_amdgcn_sched_barrier(0);
    if (t + 1 < SIMG_NT) {           // ah(t), bl(t) dead -> reload in place
#pragma unroll
      for (int mf = 0; mf < 8; mf++)
        ahr[mf] = *reinterpret_cast<const u32x4*>(Agh + nxt + aoff + mf * 64);
#pragma unroll
      for (int nf = 0; nf < 4; nf++)
        blr[nf] = *reinterpret_cast<const u32x4*>(Bgl + nxt + boff + nf * 64);
    }
    __builtin_amdgcn_sched_barrier(0);

    // P2: lo(A) x hi(B)
    __builtin_amdgcn_s_setprio(1);
    MFMA32(alr, bhr)
    __builtin_amdgcn_s_setprio(0);
    __builtin_amdgcn_sched_barrier(0);
    if (t + 1 < SIMG_NT) {           // bh(t), al(t) dead -> reload in place
#pragma unroll
      for (int nf = 0; nf < 4; nf++)
        bhr[nf] = *reinterpret_cast<const u32x4*>(Bgh + nxt + boff + nf * 64);
#pragma unroll
      for (int mf = 0; mf < 8; mf++)
        alr[mf] = *reinterpret_cast<const u32x4*>(Agl + nxt + aoff + mf * 64);
    }
    __builtin_amdgcn_sched_barrier(0);
  }
#undef MFMA32

  // epilogue: row x column scaled C write + fused column-argmax (atomicMax)
  const float* rs = invc + (size_t)z * HW;
  const float* cs = invc + (size_t)2 * HW;
  float* C = simout + (size_t)z * HW * HW;
  unsigned long long* am = amg + (size_t)z * HW;
  int m0 = bx * 256, n0 = by * 256;
  int ncol[4];
  float csv[4];
#pragma unroll
  for (int nf = 0; nf < 4; nf++) {
    ncol[nf] = n0 + wc * 64 + nf * 16 + fcol;
    csv[nf] = cs[ncol[nf]];
  }
  float bv[4] = {-FLT_MAX, -FLT_MAX, -FLT_MAX, -FLT_MAX};
  int bi[4] = {0, 0, 0, 0};
#pragma unroll
  for (int mf = 0; mf < 8; mf++) {
    int mg = m0 + wr * 128 + mf * 16 + l16 * 4;
#pragma unroll
    for (int r = 0; r < 4; r++) {
      float sc = rs[mg + r];
#pragma unroll
      for (int nf = 0; nf < 4; nf++) {
        float val = acc[mf][nf][r] * sc * csv[nf];
        C[(size_t)(mg + r) * HW + ncol[nf]] = val;
        if (val > bv[nf]) { bv[nf] = val; bi[nf] = mg + r; }   // ascending m
      }
    }
  }
#pragma unroll
  for (int nf = 0; nf < 4; nf++) {
#pragma unroll
    for (int st = 16; st <= 32; st <<= 1) {
      float ov = __shfl_xor(bv[nf], st, 64);
      int oi = __shfl_xor(bi[nf], st, 64);
      if (ov > bv[nf] || (ov == bv[nf] && oi < bi[nf])) { bv[nf] = ov; bi[nf] = oi; }
    }
  }
  if (ln < 16) {
#pragma unroll
    for (int nf = 0; nf < 4; nf++) {
      unsigned b = __float_as_uint(bv[nf]);
      unsigned key = (b & 0x80000000u) ? ~b : (b | 0x80000000u);
      unsigned long long packed =
          ((unsigned long long)key << 32) | (unsigned)(~bi[nf]);
      atomicMax(am + ncol[nf], packed);
    }
  }
}

// votes + sim_fwd final reduce (fixed order; invxd column scale applied here)
__global__ __launch_bounds__(256) void votes_k(const unsigned long long* __restrict__ am,
                                               const int* __restrict__ mask,
                                               const float* __restrict__ sfpart,
                                               const float* __restrict__ invc,
                                               float* __restrict__ simfwd,
                                               float* __restrict__ out) {
  int xy = blockIdx.x * 256 + threadIdx.x;
  float sf = ((sfpart[xy] + sfpart[HW + xy]) + sfpart[2 * HW + xy]) + sfpart[3 * HW + xy];
  simfwd[xy] = sf * invc[2 * HW + xy];
  int vote = 0;
  for (int s = 0; s < SREF; s++) {
    unsigned long long p = am[(size_t)s * HW + xy];
    int bi = (int)(~(unsigned)p);
    vote += (mask[s * HW + bi] != 0);
  }
  out[xy] = (float)vote;
}

extern "C" void kernel_launch(void* const* d_in, const int* in_sizes, int n_in,
                              void* d_out, int out_size, void* d_ws, size_t ws_size,
                              hipStream_t stream) {
  const float* fmaps = (const float*)d_in[0];
  const int* mask = (const int*)d_in[1];
  const float* basis = (const float*)d_in[2];
  float* out = (float*)d_out;
  float* ws = (float*)d_ws;

  unsigned* fh = (unsigned*)ws;                       // blocked hi plane (3 frames)
  unsigned* fl = (unsigned*)(ws + 6291456);           // blocked lo plane
  float* invc = ws + 12595200;                        // 3*HW
  float* protos = ws + 12607552;
  float* proto = ws + 12611648;
  unsigned long long* am = (unsigned long long*)(ws + 12612672);   // 2*HW u64
  float* part = ws + 12629056;                        // 8*2048
  float* counts = ws + 12645440;                      // 2 (pad 64)
  float* sfpart = ws + 12645504;                      // 4*HW

  float* sim = out;
  float* simfwd = out + 33554432;
  float* votes = out + 33558528;
  unsigned* Ach = (unsigned*)out;                     // blocked Acomb (hi)
  unsigned* Acl = (unsigned*)(out + 786432);          // blocked Acomb (lo)
  float* bt = out + 1572864;                          // 512*1024
  unsigned* TgtH = (unsigned*)(out + 5767168);        // packed fn_tgt hi
  unsigned* TgtL = (unsigned*)(out + 7864320);        // packed fn_tgt lo
  float* pbuf = out + 9961472;                        // 24*HW partials

  // 0) zero the packed-argmax array (atomicMax is order-independent)
  hipMemsetAsync(am, 0, (size_t)SREF * HW * sizeof(unsigned long long), stream);

  // 1) fused norm+pack: refs -> fh/fl frames 0,1; target -> Tgt planes
  normpack_k<<<dim3(SREF * 64), 256, 0, stream>>>(fmaps, fh, fl, 0);
  normpack_k<<<dim3(64), 256, 0, stream>>>(fmaps + (size_t)2 * CH * HW, TgtH, TgtL, 0);

  // 2) basis transpose, then blocked Acomb: projector + padded basis
  bt_k<<<dim3(16), 256, 0, stream>>>(basis, bt);
  proj_pack_k<<<dim3(16, 16), 256, 0, stream>>>(bt, Ach, Acl);
  pack_basis_k<<<dim3(512), 256, 0, stream>>>(basis, Ach, Acl);

  // 3) batched debias: s2 partials; Xd blocks read Tgt, write fh/fl frame 2
  gemm3r_k<<<dim3(256), 512, 0, stream>>>(Ach, Acl, fh, fl, TgtH, TgtL, pbuf);
  inv2_k<<<dim3(48), 256, 0, stream>>>(pbuf, invc);

  // 4) prototype (counts fused into proto_k)
  proto_k<<<256, 256, 0, stream>>>(fh, fl, mask, invc, protos, counts);
  protomv_k<<<dim3(8, 8), 256, 0, stream>>>(Ach, Acl, protos, part);
  protonorm_k<<<1, 256, 0, stream>>>(part, counts, proto);

  // 5) sim_fwd partials (raw Xd; invxd applied in votes_k)
  simfwd_k<<<dim3(64, 4), 256, 0, stream>>>(fh, fl, proto, sfpart);

  // 6) sim (256², 3-pass, LDS-free register pipeline, row+col scale, argmax)
  simg_k<<<dim3(16, 16, 2), 512, 0, stream>>>(fh, fl, invc, sim, am);

  // 7) votes + sim_fwd final sum
  votes_k<<<16, 256, 0, stream>>>(am, mask, sfpart, invc, simfwd, votes);
}

// Round 19
// 408.003 us; speedup vs baseline: 1.1732x; 1.1732x over previous
//
#include <hip/hip_runtime.h>
#include <hip/hip_bf16.h>
#include <cfloat>

#define CH   1024
#define HW   4096
#define NSVD 500
#define TFR  3
#define SREF 2

typedef __attribute__((ext_vector_type(4))) float f32x4;
typedef __attribute__((ext_vector_type(4))) unsigned int u32x4;
typedef __attribute__((ext_vector_type(8))) short short8;

// ---------------------------------------------------------------------------
// R16 configuration (proven 408.9 us) — reverted from the R17/R18 Xd-fusion
// experiment which regressed (+70 us; register bloat in gemm3r epilogue +
// dirty frame-2 planes slowing simg).
// Split-bf16 planes in BLOCKED layout: plane[t][cb][kgrp][cl][kp4] u32.
// simg: LDS-free/barrier-free 16x16x32 register pipeline (166 us, 57% MFMA).
// gemm3r: LDS-free debias GEMM (128x256 tiles); deterministic s2 partials.
// 3-PASS numerics (hh + h*lo(B) + lo(A)*h), proven vote-safe. DETERMINISTIC.
// ws (float units): fh 0 / fl 6,291,456 / invc 12,595,200 (3*HW) /
//   protos 12,607,552 / proto 12,611,648 / am 12,612,672 (2*HW u64) /
//   part 12,629,056 (8*2048) / counts 12,645,440 / sfpart 12,645,504 (4*HW)
// d_out scratch: Ach 0, Acl 786,432, bt 1,572,864, Xd 5,767,168,
//   pbuf 9,961,472 (24*HW: refs slots 0..3 / 8..11, Xd slots 16..23)
// ---------------------------------------------------------------------------

__device__ inline unsigned bfr(float x) {        // fp32 -> bf16 bits, RNE
  unsigned u = __float_as_uint(x);
  return (u + 0x7fffu + ((u >> 16) & 1u)) >> 16;
}
__device__ inline float lores(float x, unsigned h) {
  return x - __uint_as_float(h << 16);
}
__device__ inline float vlo(unsigned ph, unsigned pl) {
  return __uint_as_float(ph << 16) + __uint_as_float(pl << 16);
}
__device__ inline float vhi(unsigned ph, unsigned pl) {
  return __uint_as_float(ph & 0xFFFF0000u) + __uint_as_float(pl & 0xFFFF0000u);
}

// Fused column-l2norm + scale + split-bf16 blocked pack (fmaps, 3 frames).
__global__ __launch_bounds__(256) void normpack_k(const float* __restrict__ src,
                                                  unsigned* __restrict__ Gh,
                                                  unsigned* __restrict__ Gl,
                                                  int fbase) {
  int t = blockIdx.x >> 6;
  int n0 = (blockIdx.x & 63) * 64;
  int tid = threadIdx.x, nl = tid & 63, r = tid >> 6;
  const float* base = src + (size_t)t * CH * HW + n0 + nl;
  float s = 0.f;
  for (int c = r; c < CH; c += 4) {
    float v = base[(size_t)c * HW];
    s += v * v;
  }
  __shared__ float red[256];
  __shared__ float inv[64];
  red[tid] = s;
  __syncthreads();
  if (r == 0)
    inv[nl] = 1.0f / fmaxf(sqrtf(red[nl] + red[nl + 64] + red[nl + 128] + red[nl + 192]), 1e-12f);
  __syncthreads();

  int cg = (tid & 15) * 4;
  int n4 = n0 + cg;
  float4 w4;
  w4.x = inv[cg]; w4.y = inv[cg + 1]; w4.z = inv[cg + 2]; w4.w = inv[cg + 3];
  int gt = fbase + t;
  for (int kg = tid >> 4; kg < 128; kg += 16) {
    const float* s0 = src + ((size_t)t * CH + kg * 8) * HW + n4;
    unsigned oh[4][4], ol[4][4];
#pragma unroll
    for (int j = 0; j < 4; j++) {
      float4 va = *reinterpret_cast<const float4*>(s0 + (size_t)(2 * j) * HW);
      float4 vb = *reinterpret_cast<const float4*>(s0 + (size_t)(2 * j + 1) * HW);
      float a[4] = {va.x * w4.x, va.y * w4.y, va.z * w4.z, va.w * w4.w};
      float b[4] = {vb.x * w4.x, vb.y * w4.y, vb.z * w4.z, vb.w * w4.w};
#pragma unroll
      for (int cc = 0; cc < 4; cc++) {
        unsigned ha = bfr(a[cc]), hb = bfr(b[cc]);
        oh[cc][j] = ha | (hb << 16);
        ol[cc][j] = bfr(lores(a[cc], ha)) | (bfr(lores(b[cc], hb)) << 16);
      }
    }
    size_t vib = (((size_t)gt * 16 + (n4 >> 8)) * 128 + kg) * 256 + (n4 & 255);
#pragma unroll
    for (int cc = 0; cc < 4; cc++) {
      *reinterpret_cast<u32x4*>(Gh + (vib + cc) * 4) = *reinterpret_cast<u32x4*>(oh[cc]);
      *reinterpret_cast<u32x4*>(Gl + (vib + cc) * 4) = *reinterpret_cast<u32x4*>(ol[cc]);
    }
  }
}

// single-frame blocked pack with precomputed inv (Xd -> frame-2 plane ptrs)
__global__ __launch_bounds__(256) void scale_pack_k(const float* __restrict__ src,
                                                    const float* __restrict__ inv,
                                                    unsigned* __restrict__ Gh,
                                                    unsigned* __restrict__ Gl) {
  int gid = blockIdx.x * 256 + threadIdx.x;
  int kg = gid >> 12;
  int n = gid & 4095;
  const float* s0 = src + (size_t)(kg * 8) * HW + n;
  float w = inv[n];
  unsigned oh[4], ol[4];
#pragma unroll
  for (int j = 0; j < 4; j++) {
    float a = s0[(size_t)(2 * j) * HW] * w;
    float b = s0[(size_t)(2 * j + 1) * HW] * w;
    unsigned ha = bfr(a), hb = bfr(b);
    oh[j] = ha | (hb << 16);
    ol[j] = bfr(lores(a, ha)) | (bfr(lores(b, hb)) << 16);
  }
  size_t vi = (((size_t)(n >> 8)) * 128 + kg) * 256 + (n & 255);
  *reinterpret_cast<u32x4*>(Gh + vi * 4) = *reinterpret_cast<u32x4*>(oh);
  *reinterpret_cast<u32x4*>(Gl + vi * 4) = *reinterpret_cast<u32x4*>(ol);
}

// bt[k][c] = (k<500) ? basis[c][k] : 0   (LDS tile transpose)
__global__ __launch_bounds__(256) void bt_k(const float* __restrict__ bas,
                                            float* __restrict__ bt) {
  int c0 = blockIdx.x * 64;
  __shared__ float tile[64][129];
  int tid = threadIdx.x;
  for (int kc = 0; kc < 512; kc += 128) {
    for (int cr = tid >> 7; cr < 64; cr += 2) {
      int k = kc + (tid & 127);
      tile[cr][tid & 127] = (k < NSVD) ? bas[(size_t)(c0 + cr) * NSVD + k] : 0.f;
    }
    __syncthreads();
    for (int kr = tid >> 6; kr < 128; kr += 4)
      bt[(size_t)(kc + kr) * 1024 + c0 + (tid & 63)] = tile[tid & 63][kr];
    __syncthreads();
  }
}

// Acomb cols 0..1023: P = I - basis@basis^T, blocked write (coalesced bt reads)
__global__ __launch_bounds__(256) void proj_pack_k(const float* __restrict__ bt,
                                                   unsigned* __restrict__ Ah,
                                                   unsigned* __restrict__ Al) {
  int m0 = blockIdx.x * 64, n0 = blockIdx.y * 64;
  int tid = threadIdx.x;
  int tx = tid & 15, ty = tid >> 4;
  int lm = tid & 63, lk = tid >> 6;
  __shared__ float As[16][64];
  __shared__ float Bs[16][64];
  float acc[4][4] = {};
  for (int k0 = 0; k0 < 512; k0 += 16) {
#pragma unroll
    for (int i = 0; i < 4; i++) {
      int k = k0 + lk * 4 + i;
      As[lk * 4 + i][lm] = bt[(size_t)k * 1024 + m0 + lm];
      Bs[lk * 4 + i][lm] = bt[(size_t)k * 1024 + n0 + lm];
    }
    __syncthreads();
#pragma unroll
    for (int kk = 0; kk < 16; kk++) {
      float a[4], b[4];
#pragma unroll
      for (int i = 0; i < 4; i++) a[i] = As[kk][ty * 4 + i];
#pragma unroll
      for (int j = 0; j < 4; j++) b[j] = Bs[kk][tx * 4 + j];
#pragma unroll
      for (int i = 0; i < 4; i++)
#pragma unroll
        for (int j = 0; j < 4; j++) acc[i][j] += a[i] * b[j];
    }
    __syncthreads();
  }
#pragma unroll
  for (int jp = 0; jp < 2; jp++) {
    int r = n0 / 2 + tx * 2 + jp;
#pragma unroll
    for (int i = 0; i < 4; i++) {
      int c = m0 + ty * 4 + i;
      float va = ((c == 2 * r) ? 1.0f : 0.0f) - acc[i][2 * jp];
      float vb = ((c == 2 * r + 1) ? 1.0f : 0.0f) - acc[i][2 * jp + 1];
      unsigned ha = bfr(va), hb = bfr(vb);
      size_t vi = ((size_t)((c >> 8) * 128 + (r >> 2)) * 256 + (c & 255)) * 4 + (r & 3);
      Ah[vi] = ha | (hb << 16);
      Al[vi] = bfr(lores(va, ha)) | (bfr(lores(vb, hb)) << 16);
    }
  }
}

// Acomb cols 1024..1535: basis zero-padded to 512 svd rows
__global__ __launch_bounds__(256) void pack_basis_k(const float* __restrict__ bas,
                                                    unsigned* __restrict__ Ah,
                                                    unsigned* __restrict__ Al) {
  int r = blockIdx.x;
  for (int m = threadIdx.x; m < 512; m += 256) {
    float b0 = (m < NSVD) ? bas[(size_t)(2 * r) * NSVD + m] : 0.f;
    float b1 = (m < NSVD) ? bas[(size_t)(2 * r + 1) * NSVD + m] : 0.f;
    unsigned h0 = bfr(b0), h1 = bfr(b1);
    int c = 1024 + m;
    size_t vi = ((size_t)((c >> 8) * 128 + (r >> 2)) * 256 + (c & 255)) * 4 + (r & 3);
    Ah[vi] = h0 | (h1 << 16);
    Al[vi] = bfr(lores(b0, h0)) | (bfr(lores(b1, h1)) << 16);
  }
}

// invc from pbuf partials (fixed-order sums -> deterministic).
__global__ __launch_bounds__(256) void inv2_k(const float* __restrict__ pbuf,
                                              float* __restrict__ invc) {
  int i = blockIdx.x * 256 + threadIdx.x;
  int s = i >> 12, n = i & 4095;
  float s2 = 0.f;
  if (s < 2) {
#pragma unroll
    for (int j = 0; j < 4; j++) s2 += pbuf[(size_t)(s * 8 + j) * HW + n];
    s2 = sqrtf(fmaxf(1.0f - s2, 0.0f));
  } else {
#pragma unroll
    for (int j = 16; j < 24; j++) s2 += pbuf[(size_t)j * HW + n];
    s2 = sqrtf(s2);
  }
  invc[i] = 1.0f / fmaxf(s2, 1e-12f);
}

// protos[s*CH+c] = sum_n mask*fn*invc; block = (s, kgrp); kg==0 also counts
__global__ __launch_bounds__(256) void proto_k(const unsigned* __restrict__ Gh,
                                               const unsigned* __restrict__ Gl,
                                               const int* __restrict__ mask,
                                               const float* __restrict__ invc,
                                               float* __restrict__ protos,
                                               float* __restrict__ counts) {
  int s = blockIdx.x >> 7, kg = blockIdx.x & 127;
  int tid = threadIdx.x;
  const u32x4* Hv = (const u32x4*)Gh + (size_t)s * 524288;
  const u32x4* Lv = (const u32x4*)Gl + (size_t)s * 524288;
  float a[8] = {};
  int cnt = 0;
  for (int n = tid; n < HW; n += 256) {
    if (mask[s * HW + n]) {
      cnt++;
      float w = invc[s * HW + n];
      size_t vi = ((size_t)(n >> 8) * 128 + kg) * 256 + (n & 255);
      u32x4 h = Hv[vi], l = Lv[vi];
#pragma unroll
      for (int j = 0; j < 4; j++) {
        a[2 * j] += vlo(h[j], l[j]) * w;
        a[2 * j + 1] += vhi(h[j], l[j]) * w;
      }
    }
  }
  __shared__ float red[256];
  for (int e = 0; e < 8; e++) {
    red[tid] = a[e];
    __syncthreads();
    for (int o = 128; o > 0; o >>= 1) {
      if (tid < o) red[tid] += red[tid + o];
      __syncthreads();
    }
    if (tid == 0) protos[s * CH + kg * 8 + e] = red[0];
    __syncthreads();
  }
  if (kg == 0) {
    red[tid] = (float)cnt;
    __syncthreads();
    for (int o = 128; o > 0; o >>= 1) {
      if (tid < o) red[tid] += red[tid + o];
      __syncthreads();
    }
    if (tid == 0) counts[s] = fmaxf(red[0], 1.0f);
  }
}

// part[kc][s*CH+c] = sum_{r in kc-chunk} P[c][k]*protos[s][k]; grid (8, 8)
__global__ __launch_bounds__(256) void protomv_k(const unsigned* __restrict__ Ah,
                                                 const unsigned* __restrict__ Al,
                                                 const float* __restrict__ protos,
                                                 float* __restrict__ part) {
  int s = blockIdx.x >> 2;
  int c = (blockIdx.x & 3) * 256 + threadIdx.x;
  int kc = blockIdx.y;
  __shared__ float w[128];
  if (threadIdx.x < 128) w[threadIdx.x] = protos[s * CH + kc * 128 + threadIdx.x];
  __syncthreads();
  float acc = 0.f;
  for (int rl = 0; rl < 64; rl++) {
    int r = kc * 64 + rl;
    size_t vi = ((size_t)((c >> 8) * 128 + (r >> 2)) * 256 + (c & 255)) * 4 + (r & 3);
    unsigned h = Ah[vi], l = Al[vi];
    acc += vlo(h, l) * w[2 * rl] + vhi(h, l) * w[2 * rl + 1];
  }
  part[kc * 2048 + s * CH + c] = acc;
}

// partial-sum reduce + mean + l2norm (1 block; counts precomputed)
__global__ __launch_bounds__(256) void protonorm_k(const float* __restrict__ part,
                                                   const float* __restrict__ counts,
                                                   float* __restrict__ proto) {
  int tid = threadIdx.x;
  __shared__ float sm[CH];
  __shared__ float red[256];
  float c0 = counts[0], c1 = counts[1];
  float ss = 0.f;
  for (int c = tid; c < CH; c += 256) {
    float p0 = 0.f, p1 = 0.f;
#pragma unroll
    for (int kc = 0; kc < 8; kc++) {
      p0 += part[kc * 2048 + c];
      p1 += part[kc * 2048 + CH + c];
    }
    float m = 0.5f * (p0 / c0 + p1 / c1);
    sm[c] = m;
    ss += m * m;
  }
  red[tid] = ss;
  __syncthreads();
  for (int o = 128; o > 0; o >>= 1) {
    if (tid < o) red[tid] += red[tid + o];
    __syncthreads();
  }
  __syncthreads();
  float inv = 1.0f / fmaxf(sqrtf(red[0]), 1e-12f);
  for (int c = tid; c < CH; c += 256) proto[c] = sm[c] * inv;
}

// sim_fwd partials: grid (64, 4) -> sfpart[q*HW + n] (deterministic)
__global__ __launch_bounds__(256) void simfwd_k(const unsigned* __restrict__ Gh,
                                                const unsigned* __restrict__ Gl,
                                                const float* __restrict__ proto,
                                                float* __restrict__ sfpart) {
  int q = blockIdx.y;
  __shared__ float p[256];
  __shared__ float red[256];
  int tid = threadIdx.x;
  p[tid] = proto[q * 256 + tid];
  __syncthreads();
  int nl = tid & 63, sub = tid >> 6;        // sub: 8-kg chunk within quarter
  int n = blockIdx.x * 64 + nl;
  const u32x4* Hv = (const u32x4*)Gh + (size_t)2 * 524288;
  const u32x4* Lv = (const u32x4*)Gl + (size_t)2 * 524288;
  float acc = 0.f;
  for (int kg = q * 32 + sub * 8; kg < q * 32 + sub * 8 + 8; kg++) {
    size_t vi = ((size_t)(n >> 8) * 128 + kg) * 256 + (n & 255);
    u32x4 h = Hv[vi], l = Lv[vi];
    int pb = (kg - q * 32) * 8;
#pragma unroll
    for (int j = 0; j < 4; j++)
      acc += vlo(h[j], l[j]) * p[pb + 2 * j] + vhi(h[j], l[j]) * p[pb + 2 * j + 1];
  }
  red[tid] = acc;
  __syncthreads();
  if (sub == 0)
    sfpart[(size_t)q * HW + n] = red[nl] + red[nl + 64] + red[nl + 128] + red[nl + 192];
}

// ---------------------------------------------------------------------------
// Debias GEMM, LDS-FREE register pipeline (simg structure): 128x256 tiles,
// 8 waves x 64x64, 3-phase rotation. Epilogue: per-column s2 partials
// (shfl + 128-float LDS combine), plain-stored to pbuf slots; Xd blocks
// (z==2) also write Xd. DETERMINISTIC.
// ---------------------------------------------------------------------------
#define G3_NT 32

__global__ __launch_bounds__(512, 2) void gemm3r_k(
    const unsigned* __restrict__ Ach, const unsigned* __restrict__ Acl,
    const unsigned* __restrict__ fh, const unsigned* __restrict__ fl,
    float* __restrict__ Xd, float* __restrict__ pbuf) {
  int orig = blockIdx.x;                       // 0..255
  int lin = (orig & 7) * 32 + (orig >> 3);     // XCD-contiguous, bijective
  int z, bx, by;
  if (lin < 128) { z = lin >> 6; bx = (lin >> 4) & 3; by = lin & 15; }
  else { int l2 = lin - 128; z = 2; bx = l2 >> 4; by = l2 & 15; }
  bool isXd = (z == 2);
  int acol0 = isXd ? bx * 128 : 1024 + bx * 128;
  int acb = acol0 >> 8, aco = acol0 & 255;

  const unsigned* Agh = Ach + (size_t)acb * 131072;
  const unsigned* Agl = Acl + (size_t)acb * 131072;
  const unsigned* Bgh = fh + (size_t)z * 2097152 + (size_t)by * 131072;
  const unsigned* Bgl = fl + (size_t)z * 2097152 + (size_t)by * 131072;

  int tid = threadIdx.x, ln = tid & 63, wv = tid >> 6;
  int wr = wv >> 2, wc = wv & 3;
  int fcol = ln & 15, l16 = ln >> 4;
  int aoff = l16 * 1024 + (aco + wr * 64 + fcol) * 4;   // + mf*64
  int boff = l16 * 1024 + (wc * 64 + fcol) * 4;         // + nf*64

  f32x4 acc[4][4] = {};
  u32x4 ahr[4], alr[4], bhr[4], blr[4];

#define MFMA16R(A, B)                                                         \
  _Pragma("unroll")                                                           \
  for (int mf = 0; mf < 4; mf++)                                              \
    _Pragma("unroll")                                                         \
    for (int nf = 0; nf < 4; nf++)                                            \
      acc[mf][nf] = __builtin_amdgcn_mfma_f32_16x16x32_bf16(                  \
          __builtin_bit_cast(short8, A[mf]), __builtin_bit_cast(short8, B[nf]), \
          acc[mf][nf], 0, 0, 0);

  // prologue: tile 0 fragments
#pragma unroll
  for (int mf = 0; mf < 4; mf++)
    ahr[mf] = *reinterpret_cast<const u32x4*>(Agh + aoff + mf * 64);
#pragma unroll
  for (int nf = 0; nf < 4; nf++)
    blr[nf] = *reinterpret_cast<const u32x4*>(Bgl + boff + nf * 64);
#pragma unroll
  for (int nf = 0; nf < 4; nf++)
    bhr[nf] = *reinterpret_cast<const u32x4*>(Bgh + boff + nf * 64);
#pragma unroll
  for (int mf = 0; mf < 4; mf++)
    alr[mf] = *reinterpret_cast<const u32x4*>(Agl + aoff + mf * 64);

  for (int t = 0; t < G3_NT; ++t) {
    int nxt = (t + 1) * 4096;

    __builtin_amdgcn_s_setprio(1);
    MFMA16R(ahr, bhr)
    __builtin_amdgcn_s_setprio(0);
    __builtin_amdgcn_sched_barrier(0);

    __builtin_amdgcn_s_setprio(1);
    MFMA16R(ahr, blr)
    __builtin_amdgcn_s_setprio(0);
    __builtin_amdgcn_sched_barrier(0);
    if (t + 1 < G3_NT) {
#pragma unroll
      for (int mf = 0; mf < 4; mf++)
        ahr[mf] = *reinterpret_cast<const u32x4*>(Agh + nxt + aoff + mf * 64);
#pragma unroll
      for (int nf = 0; nf < 4; nf++)
        blr[nf] = *reinterpret_cast<const u32x4*>(Bgl + nxt + boff + nf * 64);
    }
    __builtin_amdgcn_sched_barrier(0);

    __builtin_amdgcn_s_setprio(1);
    MFMA16R(alr, bhr)
    __builtin_amdgcn_s_setprio(0);
    __builtin_amdgcn_sched_barrier(0);
    if (t + 1 < G3_NT) {
#pragma unroll
      for (int nf = 0; nf < 4; nf++)
        bhr[nf] = *reinterpret_cast<const u32x4*>(Bgh + nxt + boff + nf * 64);
#pragma unroll
      for (int mf = 0; mf < 4; mf++)
        alr[mf] = *reinterpret_cast<const u32x4*>(Agl + nxt + aoff + mf * 64);
    }
    __builtin_amdgcn_sched_barrier(0);
  }
#undef MFMA16R

  // epilogue: per-column s2; Xd blocks write C values
  int n0 = by * 256;
  float s2p[4] = {0.f, 0.f, 0.f, 0.f};
#pragma unroll
  for (int mf = 0; mf < 4; mf++) {
    int mg = bx * 128 + wr * 64 + mf * 16 + l16 * 4;
#pragma unroll
    for (int r = 0; r < 4; r++) {
#pragma unroll
      for (int nf = 0; nf < 4; nf++) {
        float v = acc[mf][nf][r];
        s2p[nf] += v * v;
        if (isXd) {
          int n = n0 + wc * 64 + nf * 16 + fcol;
          Xd[(size_t)(mg + r) * HW + n] = v;
        }
      }
    }
  }
#pragma unroll
  for (int nf = 0; nf < 4; nf++) {
    s2p[nf] += __shfl_xor(s2p[nf], 16, 64);
    s2p[nf] += __shfl_xor(s2p[nf], 32, 64);
  }
  __shared__ float sred[256];
  if (wr == 0 && l16 == 0) {
#pragma unroll
    for (int nf = 0; nf < 4; nf++) sred[wc * 64 + nf * 16 + fcol] = s2p[nf];
  }
  __syncthreads();
  if (wr == 1 && l16 == 0) {
    int slot = isXd ? 16 + bx : z * 8 + bx;
    float* dst = pbuf + (size_t)slot * HW + n0;
#pragma unroll
    for (int nf = 0; nf < 4; nf++) {
      int col = wc * 64 + nf * 16 + fcol;
      dst[col] = sred[col] + s2p[nf];
    }
  }
}

// ---------------------------------------------------------------------------
// sim GEMM (proven): 256x256 tile, 8 waves, 3-pass, LDS-FREE,
// 16x16x32 MFMA, in-place register rotation, fused atomic argmax.
// ---------------------------------------------------------------------------
#define SIMG_NT 32

__global__ __launch_bounds__(512, 2) void simg_k(
    const unsigned* __restrict__ Gh, const unsigned* __restrict__ Gl,
    const float* __restrict__ invc, float* __restrict__ simout,
    unsigned long long* __restrict__ amg) {
  int orig = (blockIdx.z * 16 + blockIdx.y) * 16 + blockIdx.x;
  int lin = (orig & 7) * 64 + (orig >> 3);         // XCD-contiguous, bijective
  int z = lin >> 8, bx = (lin >> 4) & 15, by = lin & 15;

  const unsigned* Agh = Gh + (size_t)z * 2097152 + (size_t)bx * 131072;
  const unsigned* Agl = Gl + (size_t)z * 2097152 + (size_t)bx * 131072;
  const unsigned* Bgh = Gh + (size_t)2 * 2097152 + (size_t)by * 131072;
  const unsigned* Bgl = Gl + (size_t)2 * 2097152 + (size_t)by * 131072;

  int tid = threadIdx.x, ln = tid & 63, wv = tid >> 6;
  int wr = wv >> 2, wc = wv & 3;
  int fcol = ln & 15, l16 = ln >> 4;
  int aoff = l16 * 1024 + (wr * 128 + fcol) * 4;   // + mf*64 (u32 units)
  int boff = l16 * 1024 + (wc * 64 + fcol) * 4;    // + nf*64

  f32x4 acc[8][4] = {};
  u32x4 ahr[8], alr[8], bhr[4], blr[4];

#define MFMA32(A, B)                                                          \
  _Pragma("unroll")                                                           \
  for (int mf = 0; mf < 8; mf++)                                              \
    _Pragma("unroll")                                                         \
    for (int nf = 0; nf < 4; nf++)                                            \
      acc[mf][nf] = __builtin_amdgcn_mfma_f32_16x16x32_bf16(                  \
          __builtin_bit_cast(short8, A[mf]), __builtin_bit_cast(short8, B[nf]), \
          acc[mf][nf], 0, 0, 0);

  // prologue: load tile 0 fragments (issue order: ah, bl, bh, al)
#pragma unroll
  for (int mf = 0; mf < 8; mf++)
    ahr[mf] = *reinterpret_cast<const u32x4*>(Agh + aoff + mf * 64);
#pragma unroll
  for (int nf = 0; nf < 4; nf++)
    blr[nf] = *reinterpret_cast<const u32x4*>(Bgl + boff + nf * 64);
#pragma unroll
  for (int nf = 0; nf < 4; nf++)
    bhr[nf] = *reinterpret_cast<const u32x4*>(Bgh + boff + nf * 64);
#pragma unroll
  for (int mf = 0; mf < 8; mf++)
    alr[mf] = *reinterpret_cast<const u32x4*>(Agl + aoff + mf * 64);

  for (int t = 0; t < SIMG_NT; ++t) {
    int nxt = (t + 1) * 4096;

    // P0: hi(A) x hi(B)
    __builtin_amdgcn_s_setprio(1);
    MFMA32(ahr, bhr)
    __builtin_amdgcn_s_setprio(0);
    __builtin_amdgcn_sched_barrier(0);

    // P1: hi(A) x lo(B)
    __builtin_amdgcn_s_setprio(1);
    MFMA32(ahr, blr)
    __builtin_amdgcn_s_setprio(0);
    __builtin_amdgcn_sched_barrier(0);
    if (t + 1 < SIMG_NT) {           // ah(t), bl(t) dead -> reload in place
#pragma unroll
      for (int mf = 0; mf < 8; mf++)
        ahr[mf] = *reinterpret_cast<const u32x4*>(Agh + nxt + aoff + mf * 64);
#pragma unroll
      for (int nf = 0; nf < 4; nf++)
        blr[nf] = *reinterpret_cast<const u32x4*>(Bgl + nxt + boff + nf * 64);
    }
    __builtin_amdgcn_sched_barrier(0);

    // P2: lo(A) x hi(B)
    __builtin_amdgcn_s_setprio(1);
    MFMA32(alr, bhr)
    __builtin_amdgcn_s_setprio(0);
    __builtin_amdgcn_sched_barrier(0);
    if (t + 1 < SIMG_NT) {           // bh(t), al(t) dead -> reload in place
#pragma unroll
      for (int nf = 0; nf < 4; nf++)
        bhr[nf] = *reinterpret_cast<const u32x4*>(Bgh + nxt + boff + nf * 64);
#pragma unroll
      for (int mf = 0; mf < 8; mf++)
        alr[mf] = *reinterpret_cast<const u32x4*>(Agl + nxt + aoff + mf * 64);
    }
    __builtin_amdgcn_sched_barrier(0);
  }
#undef MFMA32

  // epilogue: row-scaled C write + fused column-argmax via packed atomicMax
  const float* rs = invc + (size_t)z * HW;
  float* C = simout + (size_t)z * HW * HW;
  unsigned long long* am = amg + (size_t)z * HW;
  int m0 = bx * 256, n0 = by * 256;
  int ncol[4];
#pragma unroll
  for (int nf = 0; nf < 4; nf++) ncol[nf] = n0 + wc * 64 + nf * 16 + fcol;
  float bv[4] = {-FLT_MAX, -FLT_MAX, -FLT_MAX, -FLT_MAX};
  int bi[4] = {0, 0, 0, 0};
#pragma unroll
  for (int mf = 0; mf < 8; mf++) {
    int mg = m0 + wr * 128 + mf * 16 + l16 * 4;
#pragma unroll
    for (int r = 0; r < 4; r++) {
      float sc = rs[mg + r];
#pragma unroll
      for (int nf = 0; nf < 4; nf++) {
        float val = acc[mf][nf][r] * sc;
        C[(size_t)(mg + r) * HW + ncol[nf]] = val;
        if (val > bv[nf]) { bv[nf] = val; bi[nf] = mg + r; }   // ascending m
      }
    }
  }
#pragma unroll
  for (int nf = 0; nf < 4; nf++) {
#pragma unroll
    for (int st = 16; st <= 32; st <<= 1) {
      float ov = __shfl_xor(bv[nf], st, 64);
      int oi = __shfl_xor(bi[nf], st, 64);
      if (ov > bv[nf] || (ov == bv[nf] && oi < bi[nf])) { bv[nf] = ov; bi[nf] = oi; }
    }
  }
  if (ln < 16) {
#pragma unroll
    for (int nf = 0; nf < 4; nf++) {
      unsigned b = __float_as_uint(bv[nf]);
      unsigned key = (b & 0x80000000u) ? ~b : (b | 0x80000000u);
      unsigned long long packed =
          ((unsigned long long)key << 32) | (unsigned)(~bi[nf]);
      atomicMax(am + ncol[nf], packed);
    }
  }
}

// votes + sim_fwd final reduce (fixed order, deterministic)
__global__ __launch_bounds__(256) void votes_k(const unsigned long long* __restrict__ am,
                                               const int* __restrict__ mask,
                                               const float* __restrict__ sfpart,
                                               float* __restrict__ simfwd,
                                               float* __restrict__ out) {
  int xy = blockIdx.x * 256 + threadIdx.x;
  simfwd[xy] = ((sfpart[xy] + sfpart[HW + xy]) + sfpart[2 * HW + xy]) + sfpart[3 * HW + xy];
  int vote = 0;
  for (int s = 0; s < SREF; s++) {
    unsigned long long p = am[(size_t)s * HW + xy];
    int bi = (int)(~(unsigned)p);
    vote += (mask[s * HW + bi] != 0);
  }
  out[xy] = (float)vote;
}

extern "C" void kernel_launch(void* const* d_in, const int* in_sizes, int n_in,
                              void* d_out, int out_size, void* d_ws, size_t ws_size,
                              hipStream_t stream) {
  const float* fmaps = (const float*)d_in[0];
  const int* mask = (const int*)d_in[1];
  const float* basis = (const float*)d_in[2];
  float* out = (float*)d_out;
  float* ws = (float*)d_ws;

  unsigned* fh = (unsigned*)ws;                       // blocked hi plane
  unsigned* fl = (unsigned*)(ws + 6291456);           // blocked lo plane
  float* invc = ws + 12595200;                        // 3*HW
  float* protos = ws + 12607552;
  float* proto = ws + 12611648;
  unsigned long long* am = (unsigned long long*)(ws + 12612672);   // 2*HW u64
  float* part = ws + 12629056;                        // 8*2048
  float* counts = ws + 12645440;                      // 2 (pad 64)
  float* sfpart = ws + 12645504;                      // 4*HW

  float* sim = out;
  float* simfwd = out + 33554432;
  float* votes = out + 33558528;
  unsigned* Ach = (unsigned*)out;                     // blocked Acomb (hi)
  unsigned* Acl = (unsigned*)(out + 786432);          // blocked Acomb (lo)
  float* bt = out + 1572864;                          // 512*1024
  float* Xd = out + 5767168;                          // 1024*HW
  float* pbuf = out + 9961472;                        // 24*HW partials

  // 0) zero the packed-argmax array (atomicMax is order-independent)
  hipMemsetAsync(am, 0, (size_t)SREF * HW * sizeof(unsigned long long), stream);

  // 1) fused norm+pack: fmaps -> blocked split planes (3 frames)
  normpack_k<<<dim3(TFR * 64), 256, 0, stream>>>(fmaps, fh, fl, 0);

  // 2) basis transpose, then blocked Acomb: projector + padded basis
  bt_k<<<dim3(16), 256, 0, stream>>>(basis, bt);
  proj_pack_k<<<dim3(16, 16), 256, 0, stream>>>(bt, Ach, Acl);
  pack_basis_k<<<dim3(512), 256, 0, stream>>>(basis, Ach, Acl);

  // 3) batched debias (LDS-free register pipeline): s2 partials + Xd
  gemm3r_k<<<dim3(256), 512, 0, stream>>>(Ach, Acl, fh, fl, Xd, pbuf);
  inv2_k<<<dim3(48), 256, 0, stream>>>(pbuf, invc);

  // 4) single-pass pack: Xd -> planes frame 2
  scale_pack_k<<<dim3(2048), 256, 0, stream>>>(Xd, invc + 2 * HW,
                                               fh + (size_t)2 * 2097152,
                                               fl + (size_t)2 * 2097152);

  // 5) prototype (counts fused into proto_k)
  proto_k<<<256, 256, 0, stream>>>(fh, fl, mask, invc, protos, counts);
  protomv_k<<<dim3(8, 8), 256, 0, stream>>>(Ach, Acl, protos, part);
  protonorm_k<<<1, 256, 0, stream>>>(part, counts, proto);

  // 6) sim_fwd partials (widened 4x)
  simfwd_k<<<dim3(64, 4), 256, 0, stream>>>(fh, fl, proto, sfpart);

  // 7) sim (256², 3-pass, LDS-free 16x16 register pipeline, fused atomic argmax)
  simg_k<<<dim3(16, 16, 2), 512, 0, stream>>>(fh, fl, invc, sim, am);

  // 8) votes + sim_fwd final sum
  votes_k<<<16, 256, 0, stream>>>(am, mask, sfpart, simfwd, votes);
}